// Round 6
// baseline (466.185 us; speedup 1.0000x reference)
//
#include <hip/hip_runtime.h>
#include <hip/hip_bf16.h>

#define EMBED 1024
#define HEADS 16
#define HEAD_DIM 64
#define FFDIM 4096
#define TSEQ 2048
#define BATCH 4
#define ROWS (BATCH * TSEQ)  // 8192

typedef __bf16 bf16;
typedef __attribute__((ext_vector_type(8))) __bf16 bf16x8;
typedef __attribute__((ext_vector_type(4))) __bf16 bf16x4;
typedef __attribute__((ext_vector_type(4))) float f32x4;

typedef const __attribute__((address_space(1))) void* gvp;
typedef __attribute__((address_space(3))) void* svp;

// ---------------- weight conversion (LDS-tiled transposes, coalesced) ----------------
// Wq/Wk/Wv: [H, C=1024, Dh=64] fp32 -> WT rows (which*1024 + h*64 + d), len 1024
// Q pre-scaled by 0.125*log2(e) so attention softmax runs in exp2 domain.
__global__ __launch_bounds__(256) void conv_wqkv_t(
    const float* __restrict__ Wq, const float* __restrict__ Wk,
    const float* __restrict__ Wv, bf16* __restrict__ WqkvT) {
  __shared__ bf16 t[64][72];
  int tid = threadIdx.x;
  int k0 = blockIdx.x * 64;  // c-tile
  int head = blockIdx.y;
  int which = blockIdx.z;
  const float* src = which == 0 ? Wq : which == 1 ? Wk : Wv;
  float scale = which == 0 ? 0.125f * 1.44269504088896f : 1.0f;
  src += (size_t)head * 65536;
  bf16* dst = WqkvT + ((size_t)which * 1024 + head * 64) * 1024;
#pragma unroll
  for (int i = 0; i < 4; ++i) {
    int r = i * 16 + (tid >> 4);  // c within tile
    int c = (tid & 15) * 4;       // d
    float4 v = *(const float4*)&src[(size_t)(k0 + r) * 64 + c];
    t[c + 0][r] = (bf16)(v.x * scale);
    t[c + 1][r] = (bf16)(v.y * scale);
    t[c + 2][r] = (bf16)(v.z * scale);
    t[c + 3][r] = (bf16)(v.w * scale);
  }
  __syncthreads();
#pragma unroll
  for (int i = 0; i < 2; ++i) {
    int r = i * 32 + (tid >> 3);  // d row
    int c = (tid & 7) * 8;        // c col
    bf16x8 o;
#pragma unroll
    for (int j = 0; j < 8; ++j) o[j] = t[r][c + j];
    *(bf16x8*)&dst[(size_t)r * 1024 + k0 + c] = o;
  }
}

// W [K,N] fp32 -> WT [N,K] bf16, tiled 64x64
__global__ __launch_bounds__(256) void transpose_conv(
    const float* __restrict__ W, bf16* __restrict__ WT, int K, int N) {
  __shared__ bf16 t[64][72];
  int tid = threadIdx.x;
  int n0 = blockIdx.x * 64, k0 = blockIdx.y * 64;
#pragma unroll
  for (int i = 0; i < 4; ++i) {
    int r = i * 16 + (tid >> 4);  // k
    int c = (tid & 15) * 4;       // n
    float4 v = *(const float4*)&W[(size_t)(k0 + r) * N + n0 + c];
    t[c + 0][r] = (bf16)v.x;
    t[c + 1][r] = (bf16)v.y;
    t[c + 2][r] = (bf16)v.z;
    t[c + 3][r] = (bf16)v.w;
  }
  __syncthreads();
#pragma unroll
  for (int i = 0; i < 2; ++i) {
    int r = i * 32 + (tid >> 3);  // n
    int c = (tid & 7) * 8;        // k
    bf16x8 o;
#pragma unroll
    for (int j = 0; j < 8; ++j) o[j] = t[r][c + j];
    *(bf16x8*)&WT[(size_t)(n0 + r) * K + k0 + c] = o;
  }
}

// v [B,H,T,Dh] bf16 -> vt [B,H,Dh,T] bf16, per-bh 64x64 tiles
__global__ __launch_bounds__(256) void transpose_v(const bf16* __restrict__ v,
                                                   bf16* __restrict__ vt) {
  __shared__ bf16 t[64][72];
  int bh = blockIdx.y;
  int t0 = blockIdx.x * 64;
  const bf16* src = v + (size_t)bh * 131072;
  bf16* dst = vt + (size_t)bh * 131072;
  int tid = threadIdx.x;
#pragma unroll
  for (int i = 0; i < 2; ++i) {
    int c = tid + i * 256;
    int r = c >> 3, d0 = (c & 7) * 8;
    bf16x8 vv = *(const bf16x8*)&src[(size_t)(t0 + r) * 64 + d0];
#pragma unroll
    for (int j = 0; j < 8; ++j) t[d0 + j][r] = vv[j];
  }
  __syncthreads();
#pragma unroll
  for (int i = 0; i < 2; ++i) {
    int c = tid + i * 256;
    int r = c >> 3, s0 = (c & 7) * 8;
    bf16x8 o;
#pragma unroll
    for (int j = 0; j < 8; ++j) o[j] = t[r][s0 + j];
    *(bf16x8*)&dst[(size_t)r * 2048 + t0 + s0] = o;
  }
}

// ---------------- layernorm (fp32 in -> bf16 out) ----------------
__global__ __launch_bounds__(256) void ln_kernel(
    const float* __restrict__ x, const float* __restrict__ g,
    const float* __restrict__ bta, bf16* __restrict__ out) {
  int row = blockIdx.x;
  const float* xr = x + (size_t)row * EMBED;
  float4 v = ((const float4*)xr)[threadIdx.x];
  float s1 = v.x + v.y + v.z + v.w;
  float s2 = v.x * v.x + v.y * v.y + v.z * v.z + v.w * v.w;
#pragma unroll
  for (int off = 1; off < 64; off <<= 1) {
    s1 += __shfl_xor(s1, off);
    s2 += __shfl_xor(s2, off);
  }
  __shared__ float red[8];
  int wid = threadIdx.x >> 6;
  int lane = threadIdx.x & 63;
  if (lane == 0) {
    red[wid * 2] = s1;
    red[wid * 2 + 1] = s2;
  }
  __syncthreads();
  s1 = red[0] + red[2] + red[4] + red[6];
  s2 = red[1] + red[3] + red[5] + red[7];
  float mu = s1 * (1.0f / EMBED);
  float var = s2 * (1.0f / EMBED) - mu * mu;
  float rs = rsqrtf(var + 1e-5f);
  float4 gv = ((const float4*)g)[threadIdx.x];
  float4 bv = ((const float4*)bta)[threadIdx.x];
  bf16x4 o;
  o[0] = (bf16)((v.x - mu) * rs * gv.x + bv.x);
  o[1] = (bf16)((v.y - mu) * rs * gv.y + bv.y);
  o[2] = (bf16)((v.z - mu) * rs * gv.z + bv.z);
  o[3] = (bf16)((v.w - mu) * rs * gv.w + bv.w);
  *(bf16x4*)(out + (size_t)row * EMBED + threadIdx.x * 4) = o;
}

// ---------------- 256x256 GEMM, BK=32, 3 LDS buffers, counted vmcnt ----------------
// C[M,N] = A[M,K] * BT[N,K]^T. 512 threads = 8 waves (2M x 4N), wave tile 128x64.
// 2-deep prefetch: compute tile t from buf[t%3] while tile t+2 streams into
// buf[(t+2)%3] (whose readers finished at the top-of-t barrier). vmcnt(4) at
// tile top == "previous tile fully landed" (4 gload_lds per wave per tile).
// LDS swizzle: byte ^= (row&3)<<4 (write via inverse-swizzled global source).
// EPI 0: fused QKV scatter (col<1024 -> q, <2048 -> k, else v normal layout)
// EPI 3: bf16 out = relu(acc + bias)
template <int EPI>
__global__ __launch_bounds__(512, 2) void gemm256(
    const bf16* __restrict__ A, const bf16* __restrict__ BT,
    bf16* __restrict__ Cb, const float* __restrict__ bias, int M, int N,
    int K) {
  __shared__ __attribute__((aligned(16))) char lds[98304];  // 3 x (A16K + B16K)
  int gx = gridDim.x;
  int nwg = gx * gridDim.y;
  int wgid = blockIdx.y * gx + blockIdx.x;
  int cpx = nwg >> 3;
  int swz = (wgid & 7) * cpx + (wgid >> 3);
  int m0 = (swz / gx) * 256, n0 = (swz % gx) * 256;
  int tid = threadIdx.x;
  int lane = tid & 63, wid = tid >> 6;
  int lr = lane & 15, lg = lane >> 4;
  int wrM = (wid >> 2) * 128;  // wave M base: 0 or 128
  int wcN = (wid & 3) * 64;    // wave N base: 0/64/128/192
  int crow = lane >> 2;        // staging row within 16-row chunk
  int slotg = (lane & 3) ^ (crow & 3);  // inverse-swizzled global 16B slot
  int NT = K >> 5;
  size_t rb = (size_t)K * 2;  // bytes per row of A / BT

  auto stageT = [&](int t) {
    char* dst = lds + ((unsigned)t % 3u) * 32768u;
#pragma unroll
    for (int q = 0; q < 2; ++q) {
      int c = wid * 2 + q;  // chunk 0..15 (16 rows each)
      const char* srcA = (const char*)A + (size_t)(m0 + c * 16 + crow) * rb +
                         (size_t)t * 64 + slotg * 16;
      __builtin_amdgcn_global_load_lds((gvp)srcA, (svp)(dst + c * 1024), 16, 0,
                                       0);
      const char* srcB = (const char*)BT + (size_t)(n0 + c * 16 + crow) * rb +
                         (size_t)t * 64 + slotg * 16;
      __builtin_amdgcn_global_load_lds((gvp)srcB, (svp)(dst + 16384 + c * 1024),
                                       16, 0, 0);
    }
  };

  stageT(0);
  stageT(1);
  f32x4 acc[8][4] = {};
  int swcol = ((lg ^ (lr & 3)) * 16);
  for (int t = 0; t < NT; ++t) {
    asm volatile("s_waitcnt vmcnt(4)" ::: "memory");
    __builtin_amdgcn_s_barrier();
    const char* Ab = lds + ((unsigned)t % 3u) * 32768u;
    const char* Bb = Ab + 16384;
    bf16x8 af[8], bfr[4];
#pragma unroll
    for (int j = 0; j < 4; ++j)
      bfr[j] = *(const bf16x8*)(Bb + (wcN + j * 16 + lr) * 64 + swcol);
#pragma unroll
    for (int i = 0; i < 8; ++i)
      af[i] = *(const bf16x8*)(Ab + (wrM + i * 16 + lr) * 64 + swcol);
    int tn = t + 2;
    stageT(tn < NT ? tn : tn - NT);  // wrap keeps vmcnt counts uniform
    __builtin_amdgcn_s_setprio(1);
#pragma unroll
    for (int i = 0; i < 8; ++i)
#pragma unroll
      for (int j = 0; j < 4; ++j)
        acc[i][j] = __builtin_amdgcn_mfma_f32_16x16x32_bf16(af[i], bfr[j],
                                                            acc[i][j], 0, 0, 0);
    __builtin_amdgcn_s_setprio(0);
  }
  asm volatile("s_waitcnt vmcnt(0)" ::: "memory");
#pragma unroll
  for (int i = 0; i < 8; ++i) {
#pragma unroll
    for (int j = 0; j < 4; ++j) {
#pragma unroll
      for (int r = 0; r < 4; ++r) {
        int row = m0 + wrM + i * 16 + lg * 4 + r;
        int col = n0 + wcN + j * 16 + lr;
        float v = acc[i][j][r];
        if (EPI == 0) {
          int which = col >> 10, cc = col & 1023;
          int b = row >> 11, tt = row & 2047, h = cc >> 6, d = cc & 63;
          bf16* dst = Cb + (size_t)which * 8388608;
          dst[((size_t)((b << 4) + h) * TSEQ + tt) * HEAD_DIM + d] = (bf16)v;
        } else {
          size_t o = (size_t)row * N + col;
          float u = v + bias[col];
          Cb[o] = (bf16)(u > 0.f ? u : 0.f);
        }
      }
    }
  }
}

// ---------------- GEMM (m97 structure + XCD swizzle) for N=1024 cases ----------------
// EPI 2: fp32 out = resid + bias + acc
template <int EPI>
__global__ __launch_bounds__(256) void gemm_bf16(
    const bf16* __restrict__ A, const bf16* __restrict__ BT,
    float* __restrict__ Cf, bf16* __restrict__ Cb,
    const float* __restrict__ bias, const float* __restrict__ resid, int M,
    int N, int K) {
  __shared__ __attribute__((aligned(16))) bf16 As[128 * 32];
  __shared__ __attribute__((aligned(16))) bf16 Bs[128 * 32];
  int gx = gridDim.x;
  int nwg = gx * gridDim.y;
  int wgid = blockIdx.y * gx + blockIdx.x;
  int cpx = nwg >> 3;
  int swz = (wgid & 7) * cpx + (wgid >> 3);
  int m0 = (swz / gx) * 128, n0 = (swz % gx) * 128;
  int tid = threadIdx.x;
  int lane = tid & 63, wid = tid >> 6;
  int lr = lane & 15, lg = lane >> 4;
  int wr = (wid >> 1) * 64, wc = (wid & 1) * 64;
  int srow = lane >> 2;
  int sk = (lane & 3) * 8;
  f32x4 acc[4][4] = {};
  for (int kt = 0; kt < K; kt += 32) {
#pragma unroll
    for (int i = 0; i < 2; ++i) {
      int c = wid * 2 + i;
      int row = c * 16 + srow;
      const bf16* ga = &A[(size_t)(m0 + row) * K + kt + sk];
      const bf16* gb = &BT[(size_t)(n0 + row) * K + kt + sk];
      __builtin_amdgcn_global_load_lds((gvp)(const void*)ga,
                                       (svp)(void*)&As[c * 512], 16, 0, 0);
      __builtin_amdgcn_global_load_lds((gvp)(const void*)gb,
                                       (svp)(void*)&Bs[c * 512], 16, 0, 0);
    }
    __syncthreads();
    bf16x8 af[4], bfr[4];
#pragma unroll
    for (int i = 0; i < 4; ++i) {
      af[i] = *(const bf16x8*)&As[(wr + i * 16 + lr) * 32 + lg * 8];
      bfr[i] = *(const bf16x8*)&Bs[(wc + i * 16 + lr) * 32 + lg * 8];
    }
#pragma unroll
    for (int ar = 0; ar < 4; ++ar)
#pragma unroll
      for (int br = 0; br < 4; ++br)
        acc[ar][br] = __builtin_amdgcn_mfma_f32_16x16x32_bf16(
            af[ar], bfr[br], acc[ar][br], 0, 0, 0);
    __syncthreads();
  }
#pragma unroll
  for (int ar = 0; ar < 4; ++ar) {
#pragma unroll
    for (int br = 0; br < 4; ++br) {
#pragma unroll
      for (int r = 0; r < 4; ++r) {
        int row = m0 + wr + ar * 16 + lg * 4 + r;
        int col = n0 + wc + br * 16 + lr;
        float v = acc[ar][br][r];
        size_t o = (size_t)row * N + col;
        Cf[o] = resid[o] + bias[col] + v;
      }
    }
  }
}

// ---------------- causal flash attention: QBLK=128, 4 waves, rg=2, fixed-shift softmax ----
__global__ __launch_bounds__(256) void attn_kernel(
    const bf16* __restrict__ q, const bf16* __restrict__ k,
    const bf16* __restrict__ vt, bf16* __restrict__ out) {
  __shared__ __attribute__((aligned(16))) bf16 Ks[64][68];
  __shared__ __attribute__((aligned(16))) bf16 Vs[64][68];
  __shared__ __attribute__((aligned(16))) bf16 Ps[4][32][68];
  int bh = blockIdx.x;
  int b = bh >> 4, h = bh & 15;
  const bf16* qb = q + (size_t)bh * TSEQ * HEAD_DIM;
  const bf16* kb = k + (size_t)bh * TSEQ * HEAD_DIM;
  const bf16* vb = vt + (size_t)bh * HEAD_DIM * TSEQ;
  int tid = threadIdx.x, lane = tid & 63, w = tid >> 6;
  int lr = lane & 15, lg = lane >> 4;
  int Q = 15 - blockIdx.y;
  int tw = Q * 128 + w * 32;
  bf16x8 aq[2][2];
#pragma unroll
  for (int rg = 0; rg < 2; ++rg)
#pragma unroll
    for (int kc = 0; kc < 2; ++kc)
      aq[rg][kc] = *(const bf16x8*)&qb[(size_t)(tw + rg * 16 + lr) * HEAD_DIM +
                                       kc * 32 + lg * 8];
  f32x4 o[2][4] = {};
  float lrow[2][4] = {};
  int nj = 2 * Q + 2;
  for (int j = 0; j < nj; ++j) {
#pragma unroll
    for (int i = 0; i < 2; ++i) {
      int c = tid + i * 256;
      int rr = c >> 3, ko = (c & 7) * 8;
      *(bf16x8*)&Ks[rr][ko] =
          *(const bf16x8*)&kb[(size_t)(j * 64 + rr) * HEAD_DIM + ko];
      *(bf16x8*)&Vs[rr][ko] =
          *(const bf16x8*)&vb[(size_t)rr * TSEQ + j * 64 + ko];
    }
    __syncthreads();
    f32x4 s[2][4] = {};
#pragma unroll
    for (int nb = 0; nb < 4; ++nb) {
#pragma unroll
      for (int kc = 0; kc < 2; ++kc) {
        bf16x8 bk = *(const bf16x8*)&Ks[nb * 16 + lr][kc * 32 + lg * 8];
        s[0][nb] = __builtin_amdgcn_mfma_f32_16x16x32_bf16(aq[0][kc], bk,
                                                           s[0][nb], 0, 0, 0);
        s[1][nb] = __builtin_amdgcn_mfma_f32_16x16x32_bf16(aq[1][kc], bk,
                                                           s[1][nb], 0, 0, 0);
      }
    }
    if (j >= 2 * Q) {
#pragma unroll
      for (int rg = 0; rg < 2; ++rg)
#pragma unroll
        for (int nb = 0; nb < 4; ++nb)
#pragma unroll
          for (int r = 0; r < 4; ++r) {
            int sg = j * 64 + nb * 16 + lr;
            int tg = tw + rg * 16 + lg * 4 + r;
            if (sg > tg) s[rg][nb][r] = -1e30f;
          }
    }
#pragma unroll
    for (int rg = 0; rg < 2; ++rg) {
      float p[4][4];
#pragma unroll
      for (int r = 0; r < 4; ++r) {
        float su = 0.f;
#pragma unroll
        for (int nb = 0; nb < 4; ++nb) {
          p[nb][r] = exp2f(s[rg][nb][r] - 8.0f);
          su += p[nb][r];
        }
#pragma unroll
        for (int off = 1; off < 16; off <<= 1) su += __shfl_xor(su, off);
        lrow[rg][r] += su;
      }
#pragma unroll
      for (int nb = 0; nb < 4; ++nb)
#pragma unroll
        for (int r = 0; r < 4; ++r)
          Ps[w][rg * 16 + lg * 4 + r][nb * 16 + lr] = (bf16)p[nb][r];
    }
#pragma unroll
    for (int kc = 0; kc < 2; ++kc) {
      bf16x8 pa0 = *(const bf16x8*)&Ps[w][lr][kc * 32 + lg * 8];
      bf16x8 pa1 = *(const bf16x8*)&Ps[w][16 + lr][kc * 32 + lg * 8];
#pragma unroll
      for (int br = 0; br < 4; ++br) {
        bf16x8 bv = *(const bf16x8*)&Vs[br * 16 + lr][kc * 32 + lg * 8];
        o[0][br] =
            __builtin_amdgcn_mfma_f32_16x16x32_bf16(pa0, bv, o[0][br], 0, 0, 0);
        o[1][br] =
            __builtin_amdgcn_mfma_f32_16x16x32_bf16(pa1, bv, o[1][br], 0, 0, 0);
      }
    }
    __syncthreads();
  }
#pragma unroll
  for (int rg = 0; rg < 2; ++rg)
#pragma unroll
    for (int br = 0; br < 4; ++br)
#pragma unroll
      for (int r = 0; r < 4; ++r) {
        int t = tw + rg * 16 + lg * 4 + r;
        int d = br * 16 + lr;
        float val = o[rg][br][r] / lrow[rg][r];
        out[((size_t)(b * TSEQ) + t) * EMBED + h * HEAD_DIM + d] = (bf16)val;
      }
}

// ---------------- launch ----------------
extern "C" void kernel_launch(void* const* d_in, const int* in_sizes, int n_in,
                              void* d_out, int out_size, void* d_ws,
                              size_t ws_size, hipStream_t stream) {
  const float* x = (const float*)d_in[0];
  const float* Wq = (const float*)d_in[1];
  const float* Wk = (const float*)d_in[2];
  const float* Wv = (const float*)d_in[3];
  const float* Wo = (const float*)d_in[4];
  const float* bo = (const float*)d_in[5];
  const float* W1 = (const float*)d_in[6];
  const float* b1 = (const float*)d_in[7];
  const float* W2 = (const float*)d_in[8];
  const float* b2 = (const float*)d_in[9];
  const float* g1 = (const float*)d_in[10];
  const float* be1 = (const float*)d_in[11];
  const float* g2 = (const float*)d_in[12];
  const float* be2 = (const float*)d_in[13];
  float* out = (float*)d_out;
  char* ws = (char*)d_ws;

  const size_t U = 16777216;  // 16 MiB
  bf16* h = (bf16*)(ws + 0 * U);
  bf16* qb = (bf16*)(ws + 1 * U);
  bf16* vtb = (bf16*)(ws + 0 * U);
  bf16* vnb = (bf16*)(ws + 3 * U);
  bf16* ao = (bf16*)(ws + 3 * U);
  float* x1 = (float*)(ws + 4 * U);
  bf16* h2 = (bf16*)(ws + 6 * U);
  bf16* ff1 = (bf16*)(ws + 0 * U);
  char* wbase = ws + 7 * U;
  bf16* WqkvT = (bf16*)(wbase);           // 6 MB
  bf16* WoT = (bf16*)(wbase + 6291456);   // 2 MB
  bf16* W1T = (bf16*)(wbase + 8388608);   // 8 MB
  bf16* W2T = (bf16*)(wbase + 16777216);  // 8 MB

  hipLaunchKernelGGL(conv_wqkv_t, dim3(16, 16, 3), dim3(256), 0, stream, Wq,
                     Wk, Wv, WqkvT);
  hipLaunchKernelGGL(transpose_conv, dim3(16, 16), dim3(256), 0, stream, Wo,
                     WoT, 1024, 1024);
  hipLaunchKernelGGL(transpose_conv, dim3(64, 16), dim3(256), 0, stream, W1,
                     W1T, 1024, 4096);
  hipLaunchKernelGGL(transpose_conv, dim3(16, 64), dim3(256), 0, stream, W2,
                     W2T, 4096, 1024);
  hipLaunchKernelGGL(ln_kernel, dim3(8192), dim3(256), 0, stream, x, g1, be1,
                     h);
  // fused QKV projection: 256x256 pipelined GEMM, scatter epilogue
  hipLaunchKernelGGL((gemm256<0>), dim3(12, 32), dim3(512), 0, stream, h,
                     WqkvT, qb, (const float*)nullptr, ROWS, 3072, 1024);
  // v [B,H,T,D] -> vt [B,H,D,T]
  hipLaunchKernelGGL(transpose_v, dim3(32, 64), dim3(256), 0, stream, vnb,
                     vtb);
  // attention (QBLK=128, rg=2, fixed-shift softmax; longest-first grid)
  hipLaunchKernelGGL(attn_kernel, dim3(64, 16), dim3(256), 0, stream, qb,
                     qb + 8388608, vtb, ao);
  // x1 = x + ao @ Wo + bo
  hipLaunchKernelGGL((gemm_bf16<2>), dim3(8, 64), dim3(256), 0, stream, ao,
                     WoT, x1, (bf16*)nullptr, bo, x, ROWS, 1024, 1024);
  // h2 = LN2(x1)
  hipLaunchKernelGGL(ln_kernel, dim3(8192), dim3(256), 0, stream, x1, g2, be2,
                     h2);
  // ff1 = relu(h2 @ W1 + b1): 256x256 pipelined GEMM
  hipLaunchKernelGGL((gemm256<3>), dim3(16, 32), dim3(512), 0, stream, h2, W1T,
                     ff1, b1, ROWS, 4096, 1024);
  // out = x1 + ff1 @ W2 + b2
  hipLaunchKernelGGL((gemm_bf16<2>), dim3(8, 64), dim3(256), 0, stream, ff1,
                     W2T, out, (bf16*)nullptr, b2, x1, ROWS, 1024, 4096);
}

// Round 8
// 458.558 us; speedup vs baseline: 1.0166x; 1.0166x over previous
//
#include <hip/hip_runtime.h>
#include <hip/hip_bf16.h>

#define EMBED 1024
#define HEADS 16
#define HEAD_DIM 64
#define FFDIM 4096
#define TSEQ 2048
#define BATCH 4
#define ROWS (BATCH * TSEQ)  // 8192

typedef __bf16 bf16;
typedef __attribute__((ext_vector_type(8))) __bf16 bf16x8;
typedef __attribute__((ext_vector_type(4))) __bf16 bf16x4;
typedef __attribute__((ext_vector_type(4))) float f32x4;

typedef const __attribute__((address_space(1))) void* gvp;
typedef __attribute__((address_space(3))) void* svp;

// ---------------- weight conversion (LDS-tiled transposes, coalesced) ----------------
// Wq/Wk/Wv: [H, C=1024, Dh=64] fp32 -> WT rows (which*1024 + h*64 + d), len 1024
// Q pre-scaled by 0.125*log2(e) so attention softmax runs in exp2 domain.
__global__ __launch_bounds__(256) void conv_wqkv_t(
    const float* __restrict__ Wq, const float* __restrict__ Wk,
    const float* __restrict__ Wv, bf16* __restrict__ WqkvT) {
  __shared__ bf16 t[64][72];
  int tid = threadIdx.x;
  int k0 = blockIdx.x * 64;  // c-tile
  int head = blockIdx.y;
  int which = blockIdx.z;
  const float* src = which == 0 ? Wq : which == 1 ? Wk : Wv;
  float scale = which == 0 ? 0.125f * 1.44269504088896f : 1.0f;
  src += (size_t)head * 65536;
  bf16* dst = WqkvT + ((size_t)which * 1024 + head * 64) * 1024;
#pragma unroll
  for (int i = 0; i < 4; ++i) {
    int r = i * 16 + (tid >> 4);  // c within tile
    int c = (tid & 15) * 4;       // d
    float4 v = *(const float4*)&src[(size_t)(k0 + r) * 64 + c];
    t[c + 0][r] = (bf16)(v.x * scale);
    t[c + 1][r] = (bf16)(v.y * scale);
    t[c + 2][r] = (bf16)(v.z * scale);
    t[c + 3][r] = (bf16)(v.w * scale);
  }
  __syncthreads();
#pragma unroll
  for (int i = 0; i < 2; ++i) {
    int r = i * 32 + (tid >> 3);  // d row
    int c = (tid & 7) * 8;        // c col
    bf16x8 o;
#pragma unroll
    for (int j = 0; j < 8; ++j) o[j] = t[r][c + j];
    *(bf16x8*)&dst[(size_t)r * 1024 + k0 + c] = o;
  }
}

// W [K,N] fp32 -> WT [N,K] bf16, tiled 64x64
__global__ __launch_bounds__(256) void transpose_conv(
    const float* __restrict__ W, bf16* __restrict__ WT, int K, int N) {
  __shared__ bf16 t[64][72];
  int tid = threadIdx.x;
  int n0 = blockIdx.x * 64, k0 = blockIdx.y * 64;
#pragma unroll
  for (int i = 0; i < 4; ++i) {
    int r = i * 16 + (tid >> 4);  // k
    int c = (tid & 15) * 4;       // n
    float4 v = *(const float4*)&W[(size_t)(k0 + r) * N + n0 + c];
    t[c + 0][r] = (bf16)v.x;
    t[c + 1][r] = (bf16)v.y;
    t[c + 2][r] = (bf16)v.z;
    t[c + 3][r] = (bf16)v.w;
  }
  __syncthreads();
#pragma unroll
  for (int i = 0; i < 2; ++i) {
    int r = i * 32 + (tid >> 3);  // n
    int c = (tid & 7) * 8;        // k
    bf16x8 o;
#pragma unroll
    for (int j = 0; j < 8; ++j) o[j] = t[r][c + j];
    *(bf16x8*)&WT[(size_t)(n0 + r) * K + k0 + c] = o;
  }
}

// v [B,H,T,Dh] bf16 -> vt [B,H,Dh,T] bf16, per-bh 64x64 tiles
__global__ __launch_bounds__(256) void transpose_v(const bf16* __restrict__ v,
                                                   bf16* __restrict__ vt) {
  __shared__ bf16 t[64][72];
  int bh = blockIdx.y;
  int t0 = blockIdx.x * 64;
  const bf16* src = v + (size_t)bh * 131072;
  bf16* dst = vt + (size_t)bh * 131072;
  int tid = threadIdx.x;
#pragma unroll
  for (int i = 0; i < 2; ++i) {
    int c = tid + i * 256;
    int r = c >> 3, d0 = (c & 7) * 8;
    bf16x8 vv = *(const bf16x8*)&src[(size_t)(t0 + r) * 64 + d0];
#pragma unroll
    for (int j = 0; j < 8; ++j) t[d0 + j][r] = vv[j];
  }
  __syncthreads();
#pragma unroll
  for (int i = 0; i < 2; ++i) {
    int c = tid + i * 256;
    int r = c >> 3, s0 = (c & 7) * 8;
    bf16x8 o;
#pragma unroll
    for (int j = 0; j < 8; ++j) o[j] = t[r][s0 + j];
    *(bf16x8*)&dst[(size_t)r * 2048 + t0 + s0] = o;
  }
}

// ---------------- layernorm (fp32 in -> bf16 out) ----------------
__global__ __launch_bounds__(256) void ln_kernel(
    const float* __restrict__ x, const float* __restrict__ g,
    const float* __restrict__ bta, bf16* __restrict__ out) {
  int row = blockIdx.x;
  const float* xr = x + (size_t)row * EMBED;
  float4 v = ((const float4*)xr)[threadIdx.x];
  float s1 = v.x + v.y + v.z + v.w;
  float s2 = v.x * v.x + v.y * v.y + v.z * v.z + v.w * v.w;
#pragma unroll
  for (int off = 1; off < 64; off <<= 1) {
    s1 += __shfl_xor(s1, off);
    s2 += __shfl_xor(s2, off);
  }
  __shared__ float red[8];
  int wid = threadIdx.x >> 6;
  int lane = threadIdx.x & 63;
  if (lane == 0) {
    red[wid * 2] = s1;
    red[wid * 2 + 1] = s2;
  }
  __syncthreads();
  s1 = red[0] + red[2] + red[4] + red[6];
  s2 = red[1] + red[3] + red[5] + red[7];
  float mu = s1 * (1.0f / EMBED);
  float var = s2 * (1.0f / EMBED) - mu * mu;
  float rs = rsqrtf(var + 1e-5f);
  float4 gv = ((const float4*)g)[threadIdx.x];
  float4 bv = ((const float4*)bta)[threadIdx.x];
  bf16x4 o;
  o[0] = (bf16)((v.x - mu) * rs * gv.x + bv.x);
  o[1] = (bf16)((v.y - mu) * rs * gv.y + bv.y);
  o[2] = (bf16)((v.z - mu) * rs * gv.z + bv.z);
  o[3] = (bf16)((v.w - mu) * rs * gv.w + bv.w);
  *(bf16x4*)(out + (size_t)row * EMBED + threadIdx.x * 4) = o;
}

// ---------------- 256x256 GEMM, BK=32, 3 LDS buffers, 2-phase interleave ----------------
// C[M,N] = A[M,K] * BT[N,K]^T. 512 threads = 8 waves (2M x 4N), wave tile 128x64.
// Per K-step: phase A {read bfr+afA, stage A-half of t+2, barrier, 16 MFMA},
// phase B {read afB, stage B-half, barrier, 16 MFMA}. Counted vmcnt(4) at step
// top (vmcnt(0) only on the LAST step) — loads stay in flight across barriers.
// NO wrap-staging: for tn >= NT nothing is staged (the old wrap aliased the
// live buffer: (t+2-NT)%3 == t%3 for NT%3==2 — that was R7's race).
// Safety: all reads of buf (t-1)%3 are register-retired (lgkmcnt before the
// MFMAs of step t-1) before any wave passes the top barrier of step t, so
// staging buf (t+2)%3 == (t-1)%3 after that barrier cannot race.
// EPI 0: fused QKV scatter (col<1024 -> q, <2048 -> k, else v normal layout)
// EPI 3: bf16 out = relu(acc + bias)
template <int EPI>
__global__ __launch_bounds__(512, 1) void gemm256(
    const bf16* __restrict__ A, const bf16* __restrict__ BT,
    bf16* __restrict__ Cb, const float* __restrict__ bias, int M, int N,
    int K) {
  __shared__ __attribute__((aligned(16))) char lds[98304];  // 3 x (A16K + B16K)
  int gx = gridDim.x;
  int nwg = gx * gridDim.y;
  int wgid = blockIdx.y * gx + blockIdx.x;
  int cpx = nwg >> 3;
  int swz = (wgid & 7) * cpx + (wgid >> 3);
  int m0 = (swz / gx) * 256, n0 = (swz % gx) * 256;
  int tid = threadIdx.x;
  int lane = tid & 63, wid = tid >> 6;
  int lr = lane & 15, lg = lane >> 4;
  int wrM = (wid >> 2) * 128;  // wave M base: 0 or 128
  int wcN = (wid & 3) * 64;    // wave N base: 0/64/128/192
  int crow = lane >> 2;        // staging row within 16-row chunk
  int slotg = (lane & 3) ^ (crow & 3);  // inverse-swizzled global 16B slot
  int NT = K >> 5;
  size_t rb = (size_t)K * 2;  // bytes per row of A / BT

  auto stageA = [&](int t) {
    char* dst = lds + ((unsigned)t % 3u) * 32768u;
#pragma unroll
    for (int q = 0; q < 2; ++q) {
      int c = wid * 2 + q;  // chunk 0..15 (16 rows each)
      const char* srcA = (const char*)A + (size_t)(m0 + c * 16 + crow) * rb +
                         (size_t)t * 64 + slotg * 16;
      __builtin_amdgcn_global_load_lds((gvp)srcA, (svp)(dst + c * 1024), 16, 0,
                                       0);
    }
  };
  auto stageB = [&](int t) {
    char* dst = lds + ((unsigned)t % 3u) * 32768u + 16384u;
#pragma unroll
    for (int q = 0; q < 2; ++q) {
      int c = wid * 2 + q;
      const char* srcB = (const char*)BT + (size_t)(n0 + c * 16 + crow) * rb +
                         (size_t)t * 64 + slotg * 16;
      __builtin_amdgcn_global_load_lds((gvp)srcB, (svp)(dst + c * 1024), 16, 0,
                                       0);
    }
  };

  stageA(0);
  stageB(0);
  stageA(1);
  stageB(1);
  f32x4 acc[8][4] = {};
  int swcol = ((lg ^ (lr & 3)) * 16);
  for (int t = 0; t < NT; ++t) {
    if (t == NT - 1)
      asm volatile("s_waitcnt vmcnt(0)" ::: "memory");
    else
      asm volatile("s_waitcnt vmcnt(4)" ::: "memory");
    __builtin_amdgcn_s_barrier();
    __builtin_amdgcn_sched_barrier(0);
    const char* Ab = lds + ((unsigned)t % 3u) * 32768u;
    const char* Bb = Ab + 16384;
    int tn = t + 2;
    bool st = tn < NT;
    // ---- phase A ----
    bf16x8 bfr[4], afA[4], afB[4];
#pragma unroll
    for (int j = 0; j < 4; ++j)
      bfr[j] = *(const bf16x8*)(Bb + (wcN + j * 16 + lr) * 64 + swcol);
#pragma unroll
    for (int i = 0; i < 4; ++i)
      afA[i] = *(const bf16x8*)(Ab + (wrM + i * 16 + lr) * 64 + swcol);
    if (st) stageA(tn);
    __builtin_amdgcn_s_barrier();
    __builtin_amdgcn_sched_barrier(0);
    __builtin_amdgcn_s_setprio(1);
#pragma unroll
    for (int i = 0; i < 4; ++i)
#pragma unroll
      for (int j = 0; j < 4; ++j)
        acc[i][j] = __builtin_amdgcn_mfma_f32_16x16x32_bf16(afA[i], bfr[j],
                                                            acc[i][j], 0, 0, 0);
    __builtin_amdgcn_s_setprio(0);
    __builtin_amdgcn_sched_barrier(0);
    // ---- phase B ----
#pragma unroll
    for (int i = 0; i < 4; ++i)
      afB[i] = *(const bf16x8*)(Ab + (wrM + 64 + i * 16 + lr) * 64 + swcol);
    if (st) stageB(tn);
    __builtin_amdgcn_s_barrier();
    __builtin_amdgcn_sched_barrier(0);
    __builtin_amdgcn_s_setprio(1);
#pragma unroll
    for (int i = 0; i < 4; ++i)
#pragma unroll
      for (int j = 0; j < 4; ++j)
        acc[4 + i][j] = __builtin_amdgcn_mfma_f32_16x16x32_bf16(
            afB[i], bfr[j], acc[4 + i][j], 0, 0, 0);
    __builtin_amdgcn_s_setprio(0);
    __builtin_amdgcn_sched_barrier(0);
  }
#pragma unroll
  for (int i = 0; i < 8; ++i) {
#pragma unroll
    for (int j = 0; j < 4; ++j) {
#pragma unroll
      for (int r = 0; r < 4; ++r) {
        int row = m0 + wrM + i * 16 + lg * 4 + r;
        int col = n0 + wcN + j * 16 + lr;
        float v = acc[i][j][r];
        if (EPI == 0) {
          int which = col >> 10, cc = col & 1023;
          int b = row >> 11, tt = row & 2047, h = cc >> 6, d = cc & 63;
          bf16* dst = Cb + (size_t)which * 8388608;
          dst[((size_t)((b << 4) + h) * TSEQ + tt) * HEAD_DIM + d] = (bf16)v;
        } else {
          size_t o = (size_t)row * N + col;
          float u = v + bias[col];
          Cb[o] = (bf16)(u > 0.f ? u : 0.f);
        }
      }
    }
  }
}

// ---------------- GEMM (m97 structure + XCD swizzle) for N=1024 cases ----------------
// EPI 2: fp32 out = resid + bias + acc
template <int EPI>
__global__ __launch_bounds__(256) void gemm_bf16(
    const bf16* __restrict__ A, const bf16* __restrict__ BT,
    float* __restrict__ Cf, bf16* __restrict__ Cb,
    const float* __restrict__ bias, const float* __restrict__ resid, int M,
    int N, int K) {
  __shared__ __attribute__((aligned(16))) bf16 As[128 * 32];
  __shared__ __attribute__((aligned(16))) bf16 Bs[128 * 32];
  int gx = gridDim.x;
  int nwg = gx * gridDim.y;
  int wgid = blockIdx.y * gx + blockIdx.x;
  int cpx = nwg >> 3;
  int swz = (wgid & 7) * cpx + (wgid >> 3);
  int m0 = (swz / gx) * 128, n0 = (swz % gx) * 128;
  int tid = threadIdx.x;
  int lane = tid & 63, wid = tid >> 6;
  int lr = lane & 15, lg = lane >> 4;
  int wr = (wid >> 1) * 64, wc = (wid & 1) * 64;
  int srow = lane >> 2;
  int sk = (lane & 3) * 8;
  f32x4 acc[4][4] = {};
  for (int kt = 0; kt < K; kt += 32) {
#pragma unroll
    for (int i = 0; i < 2; ++i) {
      int c = wid * 2 + i;
      int row = c * 16 + srow;
      const bf16* ga = &A[(size_t)(m0 + row) * K + kt + sk];
      const bf16* gb = &BT[(size_t)(n0 + row) * K + kt + sk];
      __builtin_amdgcn_global_load_lds((gvp)(const void*)ga,
                                       (svp)(void*)&As[c * 512], 16, 0, 0);
      __builtin_amdgcn_global_load_lds((gvp)(const void*)gb,
                                       (svp)(void*)&Bs[c * 512], 16, 0, 0);
    }
    __syncthreads();
    bf16x8 af[4], bfr[4];
#pragma unroll
    for (int i = 0; i < 4; ++i) {
      af[i] = *(const bf16x8*)&As[(wr + i * 16 + lr) * 32 + lg * 8];
      bfr[i] = *(const bf16x8*)&Bs[(wc + i * 16 + lr) * 32 + lg * 8];
    }
#pragma unroll
    for (int ar = 0; ar < 4; ++ar)
#pragma unroll
      for (int br = 0; br < 4; ++br)
        acc[ar][br] = __builtin_amdgcn_mfma_f32_16x16x32_bf16(
            af[ar], bfr[br], acc[ar][br], 0, 0, 0);
    __syncthreads();
  }
#pragma unroll
  for (int ar = 0; ar < 4; ++ar) {
#pragma unroll
    for (int br = 0; br < 4; ++br) {
#pragma unroll
      for (int r = 0; r < 4; ++r) {
        int row = m0 + wr + ar * 16 + lg * 4 + r;
        int col = n0 + wc + br * 16 + lr;
        float v = acc[ar][br][r];
        size_t o = (size_t)row * N + col;
        Cf[o] = resid[o] + bias[col] + v;
      }
    }
  }
}

// ---------------- causal flash attention: QBLK=128, 4 waves, rg=2, fixed-shift softmax ----
__global__ __launch_bounds__(256) void attn_kernel(
    const bf16* __restrict__ q, const bf16* __restrict__ k,
    const bf16* __restrict__ vt, bf16* __restrict__ out) {
  __shared__ __attribute__((aligned(16))) bf16 Ks[64][68];
  __shared__ __attribute__((aligned(16))) bf16 Vs[64][68];
  __shared__ __attribute__((aligned(16))) bf16 Ps[4][32][68];
  int bh = blockIdx.x;
  int b = bh >> 4, h = bh & 15;
  const bf16* qb = q + (size_t)bh * TSEQ * HEAD_DIM;
  const bf16* kb = k + (size_t)bh * TSEQ * HEAD_DIM;
  const bf16* vb = vt + (size_t)bh * HEAD_DIM * TSEQ;
  int tid = threadIdx.x, lane = tid & 63, w = tid >> 6;
  int lr = lane & 15, lg = lane >> 4;
  int Q = 15 - blockIdx.y;
  int tw = Q * 128 + w * 32;
  bf16x8 aq[2][2];
#pragma unroll
  for (int rg = 0; rg < 2; ++rg)
#pragma unroll
    for (int kc = 0; kc < 2; ++kc)
      aq[rg][kc] = *(const bf16x8*)&qb[(size_t)(tw + rg * 16 + lr) * HEAD_DIM +
                                       kc * 32 + lg * 8];
  f32x4 o[2][4] = {};
  float lrow[2][4] = {};
  int nj = 2 * Q + 2;
  for (int j = 0; j < nj; ++j) {
#pragma unroll
    for (int i = 0; i < 2; ++i) {
      int c = tid + i * 256;
      int rr = c >> 3, ko = (c & 7) * 8;
      *(bf16x8*)&Ks[rr][ko] =
          *(const bf16x8*)&kb[(size_t)(j * 64 + rr) * HEAD_DIM + ko];
      *(bf16x8*)&Vs[rr][ko] =
          *(const bf16x8*)&vb[(size_t)rr * TSEQ + j * 64 + ko];
    }
    __syncthreads();
    f32x4 s[2][4] = {};
#pragma unroll
    for (int nb = 0; nb < 4; ++nb) {
#pragma unroll
      for (int kc = 0; kc < 2; ++kc) {
        bf16x8 bk = *(const bf16x8*)&Ks[nb * 16 + lr][kc * 32 + lg * 8];
        s[0][nb] = __builtin_amdgcn_mfma_f32_16x16x32_bf16(aq[0][kc], bk,
                                                           s[0][nb], 0, 0, 0);
        s[1][nb] = __builtin_amdgcn_mfma_f32_16x16x32_bf16(aq[1][kc], bk,
                                                           s[1][nb], 0, 0, 0);
      }
    }
    if (j >= 2 * Q) {
#pragma unroll
      for (int rg = 0; rg < 2; ++rg)
#pragma unroll
        for (int nb = 0; nb < 4; ++nb)
#pragma unroll
          for (int r = 0; r < 4; ++r) {
            int sg = j * 64 + nb * 16 + lr;
            int tg = tw + rg * 16 + lg * 4 + r;
            if (sg > tg) s[rg][nb][r] = -1e30f;
          }
    }
#pragma unroll
    for (int rg = 0; rg < 2; ++rg) {
      float p[4][4];
#pragma unroll
      for (int r = 0; r < 4; ++r) {
        float su = 0.f;
#pragma unroll
        for (int nb = 0; nb < 4; ++nb) {
          p[nb][r] = exp2f(s[rg][nb][r] - 8.0f);
          su += p[nb][r];
        }
#pragma unroll
        for (int off = 1; off < 16; off <<= 1) su += __shfl_xor(su, off);
        lrow[rg][r] += su;
      }
#pragma unroll
      for (int nb = 0; nb < 4; ++nb)
#pragma unroll
        for (int r = 0; r < 4; ++r)
          Ps[w][rg * 16 + lg * 4 + r][nb * 16 + lr] = (bf16)p[nb][r];
    }
#pragma unroll
    for (int kc = 0; kc < 2; ++kc) {
      bf16x8 pa0 = *(const bf16x8*)&Ps[w][lr][kc * 32 + lg * 8];
      bf16x8 pa1 = *(const bf16x8*)&Ps[w][16 + lr][kc * 32 + lg * 8];
#pragma unroll
      for (int br = 0; br < 4; ++br) {
        bf16x8 bv = *(const bf16x8*)&Vs[br * 16 + lr][kc * 32 + lg * 8];
        o[0][br] =
            __builtin_amdgcn_mfma_f32_16x16x32_bf16(pa0, bv, o[0][br], 0, 0, 0);
        o[1][br] =
            __builtin_amdgcn_mfma_f32_16x16x32_bf16(pa1, bv, o[1][br], 0, 0, 0);
      }
    }
    __syncthreads();
  }
#pragma unroll
  for (int rg = 0; rg < 2; ++rg)
#pragma unroll
    for (int br = 0; br < 4; ++br)
#pragma unroll
      for (int r = 0; r < 4; ++r) {
        int t = tw + rg * 16 + lg * 4 + r;
        int d = br * 16 + lr;
        float val = o[rg][br][r] / lrow[rg][r];
        out[((size_t)(b * TSEQ) + t) * EMBED + h * HEAD_DIM + d] = (bf16)val;
      }
}

// ---------------- launch ----------------
extern "C" void kernel_launch(void* const* d_in, const int* in_sizes, int n_in,
                              void* d_out, int out_size, void* d_ws,
                              size_t ws_size, hipStream_t stream) {
  const float* x = (const float*)d_in[0];
  const float* Wq = (const float*)d_in[1];
  const float* Wk = (const float*)d_in[2];
  const float* Wv = (const float*)d_in[3];
  const float* Wo = (const float*)d_in[4];
  const float* bo = (const float*)d_in[5];
  const float* W1 = (const float*)d_in[6];
  const float* b1 = (const float*)d_in[7];
  const float* W2 = (const float*)d_in[8];
  const float* b2 = (const float*)d_in[9];
  const float* g1 = (const float*)d_in[10];
  const float* be1 = (const float*)d_in[11];
  const float* g2 = (const float*)d_in[12];
  const float* be2 = (const float*)d_in[13];
  float* out = (float*)d_out;
  char* ws = (char*)d_ws;

  const size_t U = 16777216;  // 16 MiB
  bf16* h = (bf16*)(ws + 0 * U);
  bf16* qb = (bf16*)(ws + 1 * U);
  bf16* vtb = (bf16*)(ws + 0 * U);
  bf16* vnb = (bf16*)(ws + 3 * U);
  bf16* ao = (bf16*)(ws + 3 * U);
  float* x1 = (float*)(ws + 4 * U);
  bf16* h2 = (bf16*)(ws + 6 * U);
  bf16* ff1 = (bf16*)(ws + 0 * U);
  char* wbase = ws + 7 * U;
  bf16* WqkvT = (bf16*)(wbase);           // 6 MB
  bf16* WoT = (bf16*)(wbase + 6291456);   // 2 MB
  bf16* W1T = (bf16*)(wbase + 8388608);   // 8 MB
  bf16* W2T = (bf16*)(wbase + 16777216);  // 8 MB

  hipLaunchKernelGGL(conv_wqkv_t, dim3(16, 16, 3), dim3(256), 0, stream, Wq,
                     Wk, Wv, WqkvT);
  hipLaunchKernelGGL(transpose_conv, dim3(16, 16), dim3(256), 0, stream, Wo,
                     WoT, 1024, 1024);
  hipLaunchKernelGGL(transpose_conv, dim3(64, 16), dim3(256), 0, stream, W1,
                     W1T, 1024, 4096);
  hipLaunchKernelGGL(transpose_conv, dim3(16, 64), dim3(256), 0, stream, W2,
                     W2T, 4096, 1024);
  hipLaunchKernelGGL(ln_kernel, dim3(8192), dim3(256), 0, stream, x, g1, be1,
                     h);
  // fused QKV projection: 256x256 2-phase pipelined GEMM, scatter epilogue
  hipLaunchKernelGGL((gemm256<0>), dim3(12, 32), dim3(512), 0, stream, h,
                     WqkvT, qb, (const float*)nullptr, ROWS, 3072, 1024);
  // v [B,H,T,D] -> vt [B,H,D,T]
  hipLaunchKernelGGL(transpose_v, dim3(32, 64), dim3(256), 0, stream, vnb,
                     vtb);
  // attention (QBLK=128, rg=2, fixed-shift softmax; longest-first grid)
  hipLaunchKernelGGL(attn_kernel, dim3(64, 16), dim3(256), 0, stream, qb,
                     qb + 8388608, vtb, ao);
  // x1 = x + ao @ Wo + bo
  hipLaunchKernelGGL((gemm_bf16<2>), dim3(8, 64), dim3(256), 0, stream, ao,
                     WoT, x1, (bf16*)nullptr, bo, x, ROWS, 1024, 1024);
  // h2 = LN2(x1)
  hipLaunchKernelGGL(ln_kernel, dim3(8192), dim3(256), 0, stream, x1, g2, be2,
                     h2);
  // ff1 = relu(h2 @ W1 + b1): 256x256 2-phase pipelined GEMM
  hipLaunchKernelGGL((gemm256<3>), dim3(16, 32), dim3(512), 0, stream, h2, W1T,
                     ff1, b1, ROWS, 4096, 1024);
  // out = x1 + ff1 @ W2 + b2
  hipLaunchKernelGGL((gemm_bf16<2>), dim3(8, 64), dim3(256), 0, stream, ff1,
                     W2T, out, (bf16*)nullptr, b2, x1, ROWS, 1024, 4096);
}